// Round 12
// baseline (354.557 us; speedup 1.0000x reference)
//
#include <hip/hip_runtime.h>
#include <hip/hip_bf16.h>
#include <stdint.h>

// DecoderSelfAttention: B=8, S=2048, D=1024 (d_k=d_v=d_model)
// Pipeline (all bf16 MFMA, fp32 accumulate), 4 dispatches:
//   prep:    x->bf16, W->W^T bf16
//   proj:    FUSED [Q|K] = x@[Wq|Wk] (512 blk) + V^T = Wv^T@x^T (256 blk)
//   qk_p:    P' = exp(QK^T/32) causal 128^2 tiles + row-sum partials
//   pv:      out = (P' @ V) * 1/rowsum, causal K-truncation
//
// Round-11 (349.7us, PASSED) baseline. This round: parameter-only change to
// the qk_p/pv core (two-lane discipline: same sync skeleton, BK 64->32):
//   mm128b_core: ring-2 as 4 distinct 8KB __shared__ slots (32KB total, was
//   64KB), stage(T+1) = 4 async loads, counted vmcnt(4) (tail 0), leading +
//   trailing barrier per body (the 3-for-3 passing sync structure).
//   __launch_bounds__(256,3) -> 3 blocks/CU (was 2): pv is body-latency
//   bound (moves ~135MB but takes ~115us), more co-resident blocks overlap
//   barrier stalls. qk_p is near its HBM bound (~560MB effective) - flat.
// Race proof (identical scheme to Round-7/11 mm_core2):
//   RAW: body T = {stage(T+1); vmcnt(4) drains my tile-T loads; BAR} ->
//        after leading BAR every wave's tile T is in LDS.
//   WAR: stage(T+1) writes the slot last read at body T-1; those reads
//        drained (lgkmcnt 0) before body T-1's trailing BAR, which every
//        wave passes before any wave enters body T's stage.
// Swizzle (0 conflicts r1-r11): row r phys 16B-unit p holds global unit
// p ^ ((r>>1)&3) (pre-swizzled global src, linear LDS dest); reader key
// ((fm>>1)&3).
// Register lessons kept: no persistent prefetch regs (r4/r5); 512-thr proj
// at 2 waves/SIMD is AT the 256-reg cap.

typedef __bf16 bf16_t;
typedef __bf16 bf16x4 __attribute__((ext_vector_type(4)));
typedef __bf16 bf16x8 __attribute__((ext_vector_type(8)));
typedef float  floatx4 __attribute__((ext_vector_type(4)));

#define NB 8
#define SS 2048
#define DD 1024
#define INV_SCALE 0.03125f   // 1/sqrt(1024)

__device__ __forceinline__ void async_ld16(const void* g, void* l) {
  __builtin_amdgcn_global_load_lds(
      (const __attribute__((address_space(1))) void*)g,
      (__attribute__((address_space(3))) void*)l, 16, 0, 0);
}

#define BARRIER() do { asm volatile("" ::: "memory"); \
  __builtin_amdgcn_s_barrier(); asm volatile("" ::: "memory"); } while (0)

// ---------------- 256x256 alias-clean ring-4 GEMM core (r3 exact) ----------------
// C = A * B^T, A[M,K] row-major, B[N,K] row-major, both bf16, BK=32.
// nt = number of 32-wide K steps; REQUIRES nt % 4 == 0, nt >= 4.
__device__ __forceinline__ void mm256_core(
    const bf16_t* __restrict__ Ab, const bf16_t* __restrict__ Bb,
    int lda, int ldb, int nt,
    bf16_t* sA0, bf16_t* sA1, bf16_t* sA2, bf16_t* sA3,
    bf16_t* sB0, bf16_t* sB1, bf16_t* sB2, bf16_t* sB3,
    floatx4 acc[8][4]) {
  const int t    = threadIdx.x;         // 0..511
  const int lane = t & 63;
  const int wid  = t >> 6;
  const int wm   = wid >> 2;            // 0..1
  const int wn   = wid & 3;             // 0..3
  const int fm   = lane & 15;
  const int q    = lane >> 4;           // 0..3 (k-group)
  const int co   = (q ^ ((fm >> 1) & 3)) * 8;   // swizzled k-group offset

  // staging: 2 units/thread/operand; unit u: row=u>>2, src group=(u&3)^((row>>1)&3)
  size_t goA[2], goB[2]; int lo[2];
#pragma unroll
  for (int k = 0; k < 2; ++k) {
    const int u   = k * 512 + t;
    const int row = u >> 2;
    const int cg  = (u & 3) ^ ((row >> 1) & 3);
    goA[k] = (size_t)row * lda + cg * 8;
    goB[k] = (size_t)row * ldb + cg * 8;
    lo[k]  = u * 8;
  }

  auto stage = [&](bf16_t* la, bf16_t* lb, int tile) {
    const size_t ko = (size_t)tile * 32;
    async_ld16(Ab + ko + goA[0], la + lo[0]);
    async_ld16(Ab + ko + goA[1], la + lo[1]);
    async_ld16(Bb + ko + goB[0], lb + lo[0]);
    async_ld16(Bb + ko + goB[1], lb + lo[1]);
  };

  const int paOff = (wm * 128 + fm) * 32;
  const int pbOff = (wn * 64 + fm) * 32;

  // per-tile body; AP/BP = compute buffers (tile T), AN/BN = stage buffers
  // (tile T+3). All resolve to fixed __shared__ objects after inlining.
  auto body = [&] __attribute__((always_inline)) (
      const bf16_t* AP, const bf16_t* BP, bf16_t* AN, bf16_t* BN, int T) {
    if (T + 3 < nt) {
      stage(AN, BN, T + 3);
      asm volatile("s_waitcnt vmcnt(12)" ::: "memory");  // tile T landed
    } else if (T + 2 < nt) {
      asm volatile("s_waitcnt vmcnt(8)" ::: "memory");
    } else if (T + 1 < nt) {
      asm volatile("s_waitcnt vmcnt(4)" ::: "memory");
    } else {
      asm volatile("s_waitcnt vmcnt(0)" ::: "memory");
    }
    BARRIER();                           // leading: all waves' tile-T visible

    const bf16_t* pa = AP + paOff;
    const bf16_t* pb = BP + pbOff;
    bf16x8 a0[4], a1[4], bv[4];
#pragma unroll
    for (int i = 0; i < 4; ++i) a0[i] = *(const bf16x8*)(pa + i * 512 + co);
#pragma unroll
    for (int j = 0; j < 4; ++j) bv[j] = *(const bf16x8*)(pb + j * 512 + co);
    __builtin_amdgcn_sched_barrier(0);   // pin group1 (8 reads) before group2
#pragma unroll
    for (int i = 0; i < 4; ++i) a1[i] = *(const bf16x8*)(pa + (4 + i) * 512 + co);

    asm volatile("s_waitcnt lgkmcnt(4)" ::: "memory");   // a0/bv landed
    __builtin_amdgcn_sched_barrier(0);
    __builtin_amdgcn_s_setprio(1);
#pragma unroll
    for (int i = 0; i < 4; ++i)
#pragma unroll
      for (int j = 0; j < 4; ++j)
        acc[i][j] = __builtin_amdgcn_mfma_f32_16x16x32_bf16(bv[j], a0[i], acc[i][j], 0, 0, 0);
    __builtin_amdgcn_s_setprio(0);

    asm volatile("s_waitcnt lgkmcnt(0)" ::: "memory");   // a1 landed
    __builtin_amdgcn_sched_barrier(0);
    __builtin_amdgcn_s_setprio(1);
#pragma unroll
    for (int i = 0; i < 4; ++i)
#pragma unroll
      for (int j = 0; j < 4; ++j)
        acc[4 + i][j] = __builtin_amdgcn_mfma_f32_16x16x32_bf16(bv[j], a1[i], acc[4 + i][j], 0, 0, 0);
    __builtin_amdgcn_s_setprio(0);
    BARRIER();                           // trailing: reads done before slot reuse
  };

  // prologue: fill 3 ring slots
  stage(sA0, sB0, 0);
  stage(sA1, sB1, 1);
  stage(sA2, sB2, 2);

  for (int tb = 0; tb < nt; tb += 4) {
    body(sA0, sB0, sA3, sB3, tb + 0);
    body(sA1, sB1, sA0, sB0, tb + 1);
    body(sA2, sB2, sA1, sB1, tb + 2);
    body(sA3, sB3, sA2, sB2, tb + 3);
  }
}

__device__ __forceinline__ void zero_acc8(floatx4 acc[8][4]) {
#pragma unroll
  for (int i = 0; i < 8; ++i)
#pragma unroll
    for (int j = 0; j < 4; ++j)
      acc[i][j] = floatx4{0.f, 0.f, 0.f, 0.f};
}

__device__ __forceinline__ void store_c256_bf16(bf16_t* __restrict__ Cb, int ldc,
                                                floatx4 acc[8][4]) {
  const int lane = threadIdx.x & 63;
  const int wid  = threadIdx.x >> 6;
  const int wm = wid >> 2, wn = wid & 3;
  const int m0 = wm * 128 + (lane & 15);
  const int n0 = wn * 64 + (lane >> 4) * 4;
#pragma unroll
  for (int i = 0; i < 8; ++i)
#pragma unroll
    for (int j = 0; j < 4; ++j) {
      floatx4 a = acc[i][j];
      bf16x4 o = {(bf16_t)a[0], (bf16_t)a[1], (bf16_t)a[2], (bf16_t)a[3]};
      *(bf16x4*)(Cb + (size_t)(m0 + i * 16) * ldc + n0 + j * 16) = o;
    }
}

#define MM256_LDS_DECL                                                      \
  __shared__ __attribute__((aligned(16))) bf16_t sA0[8192], sA1[8192],      \
      sA2[8192], sA3[8192];                                                 \
  __shared__ __attribute__((aligned(16))) bf16_t sB0[8192], sB1[8192],      \
      sB2[8192], sB3[8192];

// ---------------- 128x128 ring-2 BK=32 GEMM core (param change of proven template) ----------------
// C = A * B^T, bf16, BK=32, 256 thr (4 waves 2x2), 64x64/wave, acc[4][4].
// nt counts 32-wide K steps; REQUIRES nt even >= 2. Ring-2 as 4 distinct 8KB
// __shared__ slots (32KB total -> 3+ blocks/CU); stage(T+1) = 4 loads;
// counted vmcnt(4) (tail 0); leading + trailing barrier per body.
__device__ __forceinline__ void mm128b_core(
    const bf16_t* __restrict__ Ab, const bf16_t* __restrict__ Bb,
    int lda, int ldb, int nt,
    bf16_t* sA0, bf16_t* sB0, bf16_t* sA1, bf16_t* sB1,
    floatx4 acc[4][4]) {
  const int t    = threadIdx.x;         // 0..255
  const int lane = t & 63;
  const int wm   = (t >> 6) >> 1;       // 0..1
  const int wn   = (t >> 6) & 1;        // 0..1
  const int fm   = lane & 15;
  const int q    = lane >> 4;           // 0..3
  const int co   = (q ^ ((fm >> 1) & 3)) * 8;   // swizzled unit offset

  // staging: 2 rounds/op; unit u = k*256+t; row=u>>2 (4 units/row);
  // phys unit p=u&3 holds global unit p^((row>>1)&3)
  size_t goA[2], goB[2]; int lo[2];
#pragma unroll
  for (int k = 0; k < 2; ++k) {
    const int u   = k * 256 + t;
    const int row = u >> 2;
    const int cg  = (u & 3) ^ ((row >> 1) & 3);
    goA[k] = (size_t)row * lda + cg * 8;
    goB[k] = (size_t)row * ldb + cg * 8;
    lo[k]  = u * 8;
  }

  auto stage = [&](bf16_t* la, bf16_t* lb, int tile) {
    const size_t ko = (size_t)tile * 32;
    async_ld16(Ab + ko + goA[0], la + lo[0]);
    async_ld16(Ab + ko + goA[1], la + lo[1]);
    async_ld16(Bb + ko + goB[0], lb + lo[0]);
    async_ld16(Bb + ko + goB[1], lb + lo[1]);
  };

  const int paOff = (wm * 64 + fm) * 32;
  const int pbOff = (wn * 64 + fm) * 32;

  auto body = [&] __attribute__((always_inline)) (
      const bf16_t* CA, const bf16_t* CB, bf16_t* SA, bf16_t* SB, int T) {
    if (T + 1 < nt) {
      stage(SA, SB, T + 1);
      asm volatile("s_waitcnt vmcnt(4)" ::: "memory");  // tile T landed (mine)
    } else {
      asm volatile("s_waitcnt vmcnt(0)" ::: "memory");
    }
    BARRIER();                                           // ...everyone's

    const bf16_t* pa = CA + paOff;
    const bf16_t* pb = CB + pbOff;
    bf16x8 af[4], bv[4];
#pragma unroll
    for (int i = 0; i < 4; ++i) af[i] = *(const bf16x8*)(pa + i * 512 + co);
#pragma unroll
    for (int j = 0; j < 4; ++j) bv[j] = *(const bf16x8*)(pb + j * 512 + co);
    asm volatile("s_waitcnt lgkmcnt(0)" ::: "memory");
    __builtin_amdgcn_sched_barrier(0);
    __builtin_amdgcn_s_setprio(1);
#pragma unroll
    for (int i = 0; i < 4; ++i)
#pragma unroll
      for (int j = 0; j < 4; ++j)
        acc[i][j] = __builtin_amdgcn_mfma_f32_16x16x32_bf16(bv[j], af[i], acc[i][j], 0, 0, 0);
    __builtin_amdgcn_s_setprio(0);
    BARRIER();   // trailing: reads done before next body stages this slot pair
  };

  stage(sA0, sB0, 0);
  for (int T = 0; T < nt; T += 2) {
    body(sA0, sB0, sA1, sB1, T);
    body(sA1, sB1, sA0, sB0, T + 1);
  }
}

__device__ __forceinline__ void zero_acc(floatx4 acc[4][4]) {
#pragma unroll
  for (int i = 0; i < 4; ++i)
#pragma unroll
    for (int j = 0; j < 4; ++j)
      acc[i][j] = floatx4{0.f, 0.f, 0.f, 0.f};
}

#define MM128_LDS_DECL                                                      \
  __shared__ __attribute__((aligned(16))) bf16_t sA0[4096], sA1[4096];      \
  __shared__ __attribute__((aligned(16))) bf16_t sB0[4096], sB1[4096];

// ---------------- fused converters: x->bf16 and W->W^T bf16 ----------------

__global__ __launch_bounds__(256) void prep(const float* __restrict__ x,
                                            const float* __restrict__ Wq,
                                            const float* __restrict__ Wk,
                                            const float* __restrict__ Wv,
                                            bf16_t* __restrict__ xb,
                                            bf16_t* __restrict__ Wt) {
  __shared__ float tile[32][33];
  const int bid = blockIdx.x;
  const int t = threadIdx.x;
  if (bid < 16384) {
    size_t i = (size_t)bid * 256 + t;
    float4 v = ((const float4*)x)[i];
    bf16x4 o = {(bf16_t)v.x, (bf16_t)v.y, (bf16_t)v.z, (bf16_t)v.w};
    ((bf16x4*)xb)[i] = o;
  } else {
    const int wb = bid - 16384;
    const int z = wb >> 10;                 // 0,1,2 -> Wq,Wk,Wv
    const int rem = wb & 1023;
    const float* W = (z == 0) ? Wq : (z == 1 ? Wk : Wv);
    bf16_t* O = Wt + (size_t)z * DD * DD;
    const int ty = t >> 3;
    const int tx = t & 7;
    const int k0 = (rem >> 5) * 32, n0 = (rem & 31) * 32;
    float4 v = *(const float4*)(W + (size_t)(k0 + ty) * DD + n0 + tx * 4);
    tile[ty][tx * 4 + 0] = v.x;
    tile[ty][tx * 4 + 1] = v.y;
    tile[ty][tx * 4 + 2] = v.z;
    tile[ty][tx * 4 + 3] = v.w;
    __syncthreads();
    bf16x4 o = {(bf16_t)tile[tx * 4 + 0][ty], (bf16_t)tile[tx * 4 + 1][ty],
                (bf16_t)tile[tx * 4 + 2][ty], (bf16_t)tile[tx * 4 + 3][ty]};
    *(bf16x4*)(O + (size_t)(n0 + ty) * DD + k0 + tx * 4) = o;
  }
}

// ---------------- FUSED projections ----------------
// bids 0..511:   [Q|K] tile (mt = bid&63 fastest, nt = bid>>6) -> QKb
// bids 512..767: V^T tile (r = bid-512: n=r&7 (XCD), m=(r>>3)&3, b=r>>5) -> VtB
// ldc = 2048 for both outputs; lda = ldb = DD; nt = 32. Hot path uniform.

__global__ __launch_bounds__(512, 2) void proj_gemm(
    const bf16_t* __restrict__ xb, const bf16_t* __restrict__ Wt,
    bf16_t* __restrict__ QKb, bf16_t* __restrict__ VtB) {
  MM256_LDS_DECL
  const int bid = blockIdx.x;
  const bf16_t* Ab;
  const bf16_t* Bb;
  bf16_t* Cb;
  if (bid < 512) {
    const int mt = bid & 63, nt2 = bid >> 6;
    Ab = xb + (size_t)mt * 256 * DD;
    Bb = Wt + (size_t)nt2 * 256 * DD;
    Cb = QKb + (size_t)mt * 256 * (2 * DD) + nt2 * 256;
  } else {
    const int r = bid - 512;
    const int n = r & 7;            // seq tile (XCD)
    const int m = (r >> 3) & 3;     // dv tile
    const int b = r >> 5;           // batch
    Ab = Wt + (size_t)2 * DD * DD + (size_t)m * 256 * DD;
    Bb = xb + (size_t)b * SS * DD + (size_t)n * 256 * DD;
    Cb = VtB + (size_t)b * DD * SS + (size_t)m * 256 * SS + n * 256;
  }
  floatx4 acc[8][4];
  zero_acc8(acc);
  mm256_core(Ab, Bb, DD, DD, DD / 32,
             sA0, sA1, sA2, sA3, sB0, sB1, sB2, sB3, acc);
  store_c256_bf16(Cb, 2048, acc);
}

// ---------------- QK^T -> P' = exp(s) bf16 (causal tiles only) + row-sum partials ----------------
// 1D grid 1088: b = bid&7 (XCD==batch), tt = 135-(bid>>3) (qi descending).

__global__ __launch_bounds__(256, 3) void qk_p(
    const bf16_t* __restrict__ Q, const bf16_t* __restrict__ K,
    bf16_t* __restrict__ P, float* __restrict__ lpart) {
  const int b  = blockIdx.x & 7;
  const int tt = 135 - (blockIdx.x >> 3);
  int qi = (int)((sqrtf(8.0f * tt + 1.0f) - 1.0f) * 0.5f);
  while ((qi + 1) * (qi + 2) / 2 <= tt) ++qi;
  while (qi * (qi + 1) / 2 > tt) --qi;
  const int ki = tt - qi * (qi + 1) / 2;

  MM128_LDS_DECL
  __shared__ float reds[2][128];
  const bf16_t* Ab = Q + ((size_t)b * SS + qi * 128) * (size_t)(2 * DD);
  const bf16_t* Bb = K + ((size_t)b * SS + ki * 128) * (size_t)(2 * DD);
  floatx4 acc[4][4];
  zero_acc(acc);
  mm128b_core(Ab, Bb, 2 * DD, 2 * DD, DD / 32, sA0, sB0, sA1, sB1, acc);

  const int lane = threadIdx.x & 63;
  const int wm = (threadIdx.x >> 6) >> 1, wn = (threadIdx.x >> 6) & 1;
  const bool diag = (ki == qi);
  bf16_t* Pb = P + (size_t)b * SS * SS;
  const int qloc0 = wm * 64 + (lane & 15);        // + i*16
  const int kvb0  = wn * 64 + (lane >> 4) * 4;    // + j*16, + reg

#pragma unroll
  for (int i = 0; i < 4; ++i) {
    const int qrow = qloc0 + i * 16;
    float partial = 0.f;
#pragma unroll
    for (int j = 0; j < 4; ++j) {
      const int kvb = kvb0 + j * 16;
      floatx4 p;
#pragma unroll
      for (int r = 0; r < 4; ++r) {
        const float s = acc[i][j][r] * INV_SCALE;
        p[r] = (diag && (kvb + r) > qrow) ? 0.f : __expf(s);
        partial += p[r];
      }
      bf16x4 o = {(bf16_t)p[0], (bf16_t)p[1], (bf16_t)p[2], (bf16_t)p[3]};
      *(bf16x4*)(Pb + (size_t)(qi * 128 + qrow) * SS + ki * 128 + kvb) = o;
    }
    partial += __shfl_xor(partial, 16);
    partial += __shfl_xor(partial, 32);
    if ((lane >> 4) == 0) reds[wn][qrow] = partial;
  }
  __syncthreads();
  const int t = threadIdx.x;
  if (t < 128) {
    size_t row = (size_t)b * SS + qi * 128 + t;
    lpart[row * 16 + ki] = reds[0][t] + reds[1][t];
  }
}

// ---------------- PV GEMM (causal-truncated K-loop), rowsum+scale folded, fp32 out ----------------
// 1D grid 1024: b = bid&7 (XCD==batch), nj = (bid>>3)&7, qi = 15-(bid>>6) desc.

__global__ __launch_bounds__(256, 3) void pv_gemm(
    const bf16_t* __restrict__ P, const bf16_t* __restrict__ Vt,
    const float* __restrict__ lpart, float* __restrict__ Out) {
  const int bid = blockIdx.x;
  const int b  = bid & 7;
  const int nj = (bid >> 3) & 7;
  const int qi = 15 - (bid >> 6);

  MM128_LDS_DECL
  __shared__ float sRl[128];
  const int t = threadIdx.x;
  if (t < 128) {
    const float* lp = lpart + ((size_t)b * SS + qi * 128 + t) * 16;
    float L = 0.f;
    for (int ci = 0; ci <= qi; ++ci) L += lp[ci];
    sRl[t] = 1.0f / L;
  }
  const bf16_t* Ab = P + (size_t)b * SS * SS + (size_t)qi * 128 * SS;
  const bf16_t* Bb = Vt + (size_t)b * DD * SS + (size_t)nj * 128 * SS;
  float* Cb = Out + (size_t)b * SS * DD + (size_t)qi * 128 * DD + nj * 128;
  floatx4 acc[4][4];
  zero_acc(acc);
  mm128b_core(Ab, Bb, SS, SS, (qi + 1) * 4, sA0, sB0, sA1, sB1, acc); // K=(qi+1)*128
  const int lane = threadIdx.x & 63;
  const int wm = (threadIdx.x >> 6) >> 1, wn = (threadIdx.x >> 6) & 1;
  const int m0 = wm * 64 + (lane & 15);          // q row
  const int n0 = wn * 64 + (lane >> 4) * 4;      // dv col
#pragma unroll
  for (int i2 = 0; i2 < 4; ++i2) {
    const float scale = sRl[m0 + i2 * 16];
    float* crow = Cb + (size_t)(m0 + i2 * 16) * DD + n0;
#pragma unroll
    for (int j = 0; j < 4; ++j) {
      floatx4 o = acc[i2][j];
      o[0] *= scale; o[1] *= scale; o[2] *= scale; o[3] *= scale;
      *(floatx4*)(crow + j * 16) = o;
    }
  }
}

// ---------------- launch ----------------

extern "C" void kernel_launch(void* const* d_in, const int* in_sizes, int n_in,
                              void* d_out, int out_size, void* d_ws, size_t ws_size,
                              hipStream_t stream) {
  const float* x  = (const float*)d_in[0];
  const float* Wq = (const float*)d_in[1];
  const float* Wk = (const float*)d_in[2];
  const float* Wv = (const float*)d_in[3];
  float* out = (float*)d_out;

  char* ws = (char*)d_ws;
  bf16_t* xb   = (bf16_t*)(ws);                      // 33,554,432  x bf16 [B*S, D]
  bf16_t* Wt   = (bf16_t*)(ws + 33554432ull);        //  6,291,456  Wq^T,Wk^T,Wv^T bf16 [N,K] each
  bf16_t* QKb  = (bf16_t*)(ws + 39845888ull);        // 67,108,864  [Q|K] bf16 [B*S, 2048]
  bf16_t* VtB  = (bf16_t*)(ws + 106954752ull);       // 33,554,432  V^T bf16 [B, D, S]
  bf16_t* Pb   = (bf16_t*)(ws + 140509184ull);       // 67,108,864  P' bf16 [B, S, S] (causal area only)
  float*  lpart= (float*)(ws + 207618048ull);        //  1,048,576  row-sum partials [B*S, 16]
  (void)in_sizes; (void)n_in; (void)out_size; (void)ws_size;

  // 1. convert x + convert/transpose weights (one dispatch)
  prep<<<16384 + 3072, 256, 0, stream>>>(x, Wq, Wk, Wv, xb, Wt);
  // 2. FUSED: [Q|K] = x @ [Wq|Wk] (512 blocks) + V^T = Wv^T@x^T (256 blocks)
  proj_gemm<<<768, 512, 0, stream>>>(xb, Wt, QKb, VtB);
  // 3. P' = exp(QK^T/32) on causal tiles + row-sum partials, XCD==batch
  qk_p<<<1088, 256, 0, stream>>>(QKb, QKb + DD, Pb, lpart);
  // 4. out = (P' @ V) * (1/rowsum), causal K-truncation, XCD==batch, nj inner
  pv_gemm<<<1024, 256, 0, stream>>>(Pb, VtB, lpart, out);
}

// Round 13
// 336.171 us; speedup vs baseline: 1.0547x; 1.0547x over previous
//
#include <hip/hip_runtime.h>
#include <hip/hip_bf16.h>
#include <stdint.h>

// DecoderSelfAttention: B=8, S=2048, D=1024 (d_k=d_v=d_model)
// Pipeline (all bf16 MFMA, fp32 accumulate), 4 dispatches:
//   prep:    x->bf16, W->W^T bf16
//   proj:    FUSED [Q|K] = x@[Wq|Wk] (512 blk) + V^T = Wv^T@x^T (256 blk)
//   qk_p:    P' = exp(QK^T/32) causal 128^2 tiles + row-sum partials
//   pv:      out = (P' @ V) * 1/rowsum, causal K-truncation
//
// FINAL / MEASURED-BEST configuration == Round 11 (349.7us, PASSED).
// r12 post-mortem: BK=32 + 3 blocks/CU for qk_p/pv was flat-to-negative
// (354.6) -> pre-committed revert. Session lever audit:
//   - reg frag double-buffer: INFEASIBLE (256 reg/wave cap; r4/r5 spills)
//   - BK=64 at 256^2: regress (r6); BK=32 at 128^2 + occupancy: flat (r12)
//   - single-barrier bodies: latent race, RETIRED (r10)
//   - deeper rings / frag pipelining: neutral (r1/r2); 256^2 attn: regress (r9)
//   - dispatch fusion: +5us, kept (r8)
//
// mm256_core (r3-exact): ring-4 BK=32 distinct __shared__ objects, 3-ahead
// staging, counted vmcnt(12)/8/4/0, leading BAR (RAW) + trailing BAR (WAR).
// mm_core2 (Round-7-exact): ring-2 BK=64 distinct objects, stage(T+1),
// counted vmcnt(8) (tail 0), leading+trailing BAR per body.
// Swizzle (0 conflicts r1-r12): row r phys 16B-unit p holds global unit
// p ^ ((r>>1)&3) (pre-swizzled global src, linear LDS dest for
// global_load_lds); reader key ((fm>>1)&3).
// Register lesson (r4/r5): 512-thr block = 2 waves/SIMD -> 256 reg/wave
// unified cap; acc(128 AGPR)+arch(128) is AT cap -> no persistent prefetch
// registers, in-body transient reads only.

typedef __bf16 bf16_t;
typedef __bf16 bf16x4 __attribute__((ext_vector_type(4)));
typedef __bf16 bf16x8 __attribute__((ext_vector_type(8)));
typedef float  floatx4 __attribute__((ext_vector_type(4)));

#define NB 8
#define SS 2048
#define DD 1024
#define INV_SCALE 0.03125f   // 1/sqrt(1024)

__device__ __forceinline__ void async_ld16(const void* g, void* l) {
  __builtin_amdgcn_global_load_lds(
      (const __attribute__((address_space(1))) void*)g,
      (__attribute__((address_space(3))) void*)l, 16, 0, 0);
}

#define BARRIER() do { asm volatile("" ::: "memory"); \
  __builtin_amdgcn_s_barrier(); asm volatile("" ::: "memory"); } while (0)

// ---------------- 256x256 alias-clean ring-4 GEMM core (r3 exact) ----------------
// C = A * B^T, A[M,K] row-major, B[N,K] row-major, both bf16, BK=32.
// nt = number of 32-wide K steps; REQUIRES nt % 4 == 0, nt >= 4.
__device__ __forceinline__ void mm256_core(
    const bf16_t* __restrict__ Ab, const bf16_t* __restrict__ Bb,
    int lda, int ldb, int nt,
    bf16_t* sA0, bf16_t* sA1, bf16_t* sA2, bf16_t* sA3,
    bf16_t* sB0, bf16_t* sB1, bf16_t* sB2, bf16_t* sB3,
    floatx4 acc[8][4]) {
  const int t    = threadIdx.x;         // 0..511
  const int lane = t & 63;
  const int wid  = t >> 6;
  const int wm   = wid >> 2;            // 0..1
  const int wn   = wid & 3;             // 0..3
  const int fm   = lane & 15;
  const int q    = lane >> 4;           // 0..3 (k-group)
  const int co   = (q ^ ((fm >> 1) & 3)) * 8;   // swizzled k-group offset

  // staging: 2 units/thread/operand; unit u: row=u>>2, src group=(u&3)^((row>>1)&3)
  size_t goA[2], goB[2]; int lo[2];
#pragma unroll
  for (int k = 0; k < 2; ++k) {
    const int u   = k * 512 + t;
    const int row = u >> 2;
    const int cg  = (u & 3) ^ ((row >> 1) & 3);
    goA[k] = (size_t)row * lda + cg * 8;
    goB[k] = (size_t)row * ldb + cg * 8;
    lo[k]  = u * 8;
  }

  auto stage = [&](bf16_t* la, bf16_t* lb, int tile) {
    const size_t ko = (size_t)tile * 32;
    async_ld16(Ab + ko + goA[0], la + lo[0]);
    async_ld16(Ab + ko + goA[1], la + lo[1]);
    async_ld16(Bb + ko + goB[0], lb + lo[0]);
    async_ld16(Bb + ko + goB[1], lb + lo[1]);
  };

  const int paOff = (wm * 128 + fm) * 32;
  const int pbOff = (wn * 64 + fm) * 32;

  // per-tile body; AP/BP = compute buffers (tile T), AN/BN = stage buffers
  // (tile T+3). All resolve to fixed __shared__ objects after inlining.
  auto body = [&] __attribute__((always_inline)) (
      const bf16_t* AP, const bf16_t* BP, bf16_t* AN, bf16_t* BN, int T) {
    if (T + 3 < nt) {
      stage(AN, BN, T + 3);
      asm volatile("s_waitcnt vmcnt(12)" ::: "memory");  // tile T landed
    } else if (T + 2 < nt) {
      asm volatile("s_waitcnt vmcnt(8)" ::: "memory");
    } else if (T + 1 < nt) {
      asm volatile("s_waitcnt vmcnt(4)" ::: "memory");
    } else {
      asm volatile("s_waitcnt vmcnt(0)" ::: "memory");
    }
    BARRIER();                           // leading: all waves' tile-T visible

    const bf16_t* pa = AP + paOff;
    const bf16_t* pb = BP + pbOff;
    bf16x8 a0[4], a1[4], bv[4];
#pragma unroll
    for (int i = 0; i < 4; ++i) a0[i] = *(const bf16x8*)(pa + i * 512 + co);
#pragma unroll
    for (int j = 0; j < 4; ++j) bv[j] = *(const bf16x8*)(pb + j * 512 + co);
    __builtin_amdgcn_sched_barrier(0);   // pin group1 (8 reads) before group2
#pragma unroll
    for (int i = 0; i < 4; ++i) a1[i] = *(const bf16x8*)(pa + (4 + i) * 512 + co);

    asm volatile("s_waitcnt lgkmcnt(4)" ::: "memory");   // a0/bv landed
    __builtin_amdgcn_sched_barrier(0);
    __builtin_amdgcn_s_setprio(1);
#pragma unroll
    for (int i = 0; i < 4; ++i)
#pragma unroll
      for (int j = 0; j < 4; ++j)
        acc[i][j] = __builtin_amdgcn_mfma_f32_16x16x32_bf16(bv[j], a0[i], acc[i][j], 0, 0, 0);
    __builtin_amdgcn_s_setprio(0);

    asm volatile("s_waitcnt lgkmcnt(0)" ::: "memory");   // a1 landed
    __builtin_amdgcn_sched_barrier(0);
    __builtin_amdgcn_s_setprio(1);
#pragma unroll
    for (int i = 0; i < 4; ++i)
#pragma unroll
      for (int j = 0; j < 4; ++j)
        acc[4 + i][j] = __builtin_amdgcn_mfma_f32_16x16x32_bf16(bv[j], a1[i], acc[4 + i][j], 0, 0, 0);
    __builtin_amdgcn_s_setprio(0);
    BARRIER();                           // trailing: reads done before slot reuse
  };

  // prologue: fill 3 ring slots
  stage(sA0, sB0, 0);
  stage(sA1, sB1, 1);
  stage(sA2, sB2, 2);

  for (int tb = 0; tb < nt; tb += 4) {
    body(sA0, sB0, sA3, sB3, tb + 0);
    body(sA1, sB1, sA0, sB0, tb + 1);
    body(sA2, sB2, sA1, sB1, tb + 2);
    body(sA3, sB3, sA2, sB2, tb + 3);
  }
}

__device__ __forceinline__ void zero_acc8(floatx4 acc[8][4]) {
#pragma unroll
  for (int i = 0; i < 8; ++i)
#pragma unroll
    for (int j = 0; j < 4; ++j)
      acc[i][j] = floatx4{0.f, 0.f, 0.f, 0.f};
}

__device__ __forceinline__ void store_c256_bf16(bf16_t* __restrict__ Cb, int ldc,
                                                floatx4 acc[8][4]) {
  const int lane = threadIdx.x & 63;
  const int wid  = threadIdx.x >> 6;
  const int wm = wid >> 2, wn = wid & 3;
  const int m0 = wm * 128 + (lane & 15);
  const int n0 = wn * 64 + (lane >> 4) * 4;
#pragma unroll
  for (int i = 0; i < 8; ++i)
#pragma unroll
    for (int j = 0; j < 4; ++j) {
      floatx4 a = acc[i][j];
      bf16x4 o = {(bf16_t)a[0], (bf16_t)a[1], (bf16_t)a[2], (bf16_t)a[3]};
      *(bf16x4*)(Cb + (size_t)(m0 + i * 16) * ldc + n0 + j * 16) = o;
    }
}

#define MM256_LDS_DECL                                                      \
  __shared__ __attribute__((aligned(16))) bf16_t sA0[8192], sA1[8192],      \
      sA2[8192], sA3[8192];                                                 \
  __shared__ __attribute__((aligned(16))) bf16_t sB0[8192], sB1[8192],      \
      sB2[8192], sB3[8192];

// ---------------- 128x128 ring-2 GEMM core v2 (Round-7 exact; qk_p / pv) ----------------
// C = A * B^T, A[M,K] row-major, B[N,K] row-major, bf16, BK=64, 256 thr
// (4 waves 2x2), acc 4x4. nt counts 64-wide K steps; REQUIRES nt even >= 2.
// Ring-2 as FOUR DISTINCT __shared__ arrays (alias-clean); stage(T+1) before
// compute(T); counted vmcnt(8) (tail 0); leading+trailing barrier per tile.
__device__ __forceinline__ void mm_core2(
    const bf16_t* __restrict__ Ab, const bf16_t* __restrict__ Bb,
    int lda, int ldb, int nt,
    bf16_t* sA0, bf16_t* sB0, bf16_t* sA1, bf16_t* sB1,
    floatx4 acc[4][4]) {
  const int t    = threadIdx.x;
  const int lane = t & 63;
  const int wm   = (t >> 6) >> 1;
  const int wn   = (t >> 6) & 1;
  const int fm   = lane & 15;
  const int q    = lane >> 4;       // 0..3
  const int xo   = fm & 7;          // per-lane XOR swizzle key

  // staging: 4 rounds/op; unit u = k*256+t; row=u>>3; cc=(u&7)^(row&7)
  size_t goA[4], goB[4]; int lo[4];
#pragma unroll
  for (int k = 0; k < 4; ++k) {
    const int u   = k * 256 + t;
    const int row = u >> 3;
    const int cc  = (u & 7) ^ (row & 7);
    goA[k] = (size_t)row * lda + cc * 8;
    goB[k] = (size_t)row * ldb + cc * 8;
    lo[k]  = u * 8;
  }

  auto stage = [&](bf16_t* la, bf16_t* lb, int tile) {
    const size_t ko = (size_t)tile * 64;
#pragma unroll
    for (int k = 0; k < 4; ++k) async_ld16(Ab + ko + goA[k], la + lo[k]);
#pragma unroll
    for (int k = 0; k < 4; ++k) async_ld16(Bb + ko + goB[k], lb + lo[k]);
  };

  const int paOff = (wm * 64 + fm) * 64;
  const int pbOff = (wn * 64 + fm) * 64;

  auto body = [&] __attribute__((always_inline)) (
      const bf16_t* CA, const bf16_t* CB, bf16_t* SA, bf16_t* SB, int T) {
    if (T + 1 < nt) {
      stage(SA, SB, T + 1);
      asm volatile("s_waitcnt vmcnt(8)" ::: "memory");  // tile T landed (mine)
    } else {
      asm volatile("s_waitcnt vmcnt(0)" ::: "memory");
    }
    BARRIER();                                           // ...everyone's

    const bf16_t* pa = CA + paOff;
    const bf16_t* pb = CB + pbOff;
#pragma unroll
    for (int h = 0; h < 2; ++h) {
      const int co = ((h * 4 + q) ^ xo) * 8;
      bf16x8 af[4], bfr[4];
#pragma unroll
      for (int i = 0; i < 4; ++i) af[i]  = *(const bf16x8*)(pa + i * 1024 + co);
#pragma unroll
      for (int j = 0; j < 4; ++j) bfr[j] = *(const bf16x8*)(pb + j * 1024 + co);
      asm volatile("s_waitcnt lgkmcnt(0)" ::: "memory");
      __builtin_amdgcn_sched_barrier(0);
      __builtin_amdgcn_s_setprio(1);
#pragma unroll
      for (int i = 0; i < 4; ++i)
#pragma unroll
        for (int j = 0; j < 4; ++j)
          acc[i][j] = __builtin_amdgcn_mfma_f32_16x16x32_bf16(bfr[j], af[i], acc[i][j], 0, 0, 0);
      __builtin_amdgcn_s_setprio(0);
    }
    BARRIER();   // trailing: reads done before next body stages this pair
  };

  stage(sA0, sB0, 0);
  for (int T = 0; T < nt; T += 2) {
    body(sA0, sB0, sA1, sB1, T);
    body(sA1, sB1, sA0, sB0, T + 1);
  }
}

__device__ __forceinline__ void zero_acc(floatx4 acc[4][4]) {
#pragma unroll
  for (int i = 0; i < 4; ++i)
#pragma unroll
    for (int j = 0; j < 4; ++j)
      acc[i][j] = floatx4{0.f, 0.f, 0.f, 0.f};
}

#define MM128_LDS_DECL                                                      \
  __shared__ __attribute__((aligned(16))) bf16_t sA0[128 * 64], sA1[128 * 64]; \
  __shared__ __attribute__((aligned(16))) bf16_t sB0[128 * 64], sB1[128 * 64];

// ---------------- fused converters: x->bf16 and W->W^T bf16 ----------------

__global__ __launch_bounds__(256) void prep(const float* __restrict__ x,
                                            const float* __restrict__ Wq,
                                            const float* __restrict__ Wk,
                                            const float* __restrict__ Wv,
                                            bf16_t* __restrict__ xb,
                                            bf16_t* __restrict__ Wt) {
  __shared__ float tile[32][33];
  const int bid = blockIdx.x;
  const int t = threadIdx.x;
  if (bid < 16384) {
    size_t i = (size_t)bid * 256 + t;
    float4 v = ((const float4*)x)[i];
    bf16x4 o = {(bf16_t)v.x, (bf16_t)v.y, (bf16_t)v.z, (bf16_t)v.w};
    ((bf16x4*)xb)[i] = o;
  } else {
    const int wb = bid - 16384;
    const int z = wb >> 10;                 // 0,1,2 -> Wq,Wk,Wv
    const int rem = wb & 1023;
    const float* W = (z == 0) ? Wq : (z == 1 ? Wk : Wv);
    bf16_t* O = Wt + (size_t)z * DD * DD;
    const int ty = t >> 3;
    const int tx = t & 7;
    const int k0 = (rem >> 5) * 32, n0 = (rem & 31) * 32;
    float4 v = *(const float4*)(W + (size_t)(k0 + ty) * DD + n0 + tx * 4);
    tile[ty][tx * 4 + 0] = v.x;
    tile[ty][tx * 4 + 1] = v.y;
    tile[ty][tx * 4 + 2] = v.z;
    tile[ty][tx * 4 + 3] = v.w;
    __syncthreads();
    bf16x4 o = {(bf16_t)tile[tx * 4 + 0][ty], (bf16_t)tile[tx * 4 + 1][ty],
                (bf16_t)tile[tx * 4 + 2][ty], (bf16_t)tile[tx * 4 + 3][ty]};
    *(bf16x4*)(O + (size_t)(n0 + ty) * DD + k0 + tx * 4) = o;
  }
}

// ---------------- FUSED projections ----------------
// bids 0..511:   [Q|K] tile (mt = bid&63 fastest, nt = bid>>6) -> QKb
// bids 512..767: V^T tile (r = bid-512: n=r&7 (XCD), m=(r>>3)&3, b=r>>5) -> VtB
// ldc = 2048 for both outputs; lda = ldb = DD; nt = 32. Hot path uniform.

__global__ __launch_bounds__(512, 2) void proj_gemm(
    const bf16_t* __restrict__ xb, const bf16_t* __restrict__ Wt,
    bf16_t* __restrict__ QKb, bf16_t* __restrict__ VtB) {
  MM256_LDS_DECL
  const int bid = blockIdx.x;
  const bf16_t* Ab;
  const bf16_t* Bb;
  bf16_t* Cb;
  if (bid < 512) {
    const int mt = bid & 63, nt2 = bid >> 6;
    Ab = xb + (size_t)mt * 256 * DD;
    Bb = Wt + (size_t)nt2 * 256 * DD;
    Cb = QKb + (size_t)mt * 256 * (2 * DD) + nt2 * 256;
  } else {
    const int r = bid - 512;
    const int n = r & 7;            // seq tile (XCD)
    const int m = (r >> 3) & 3;     // dv tile
    const int b = r >> 5;           // batch
    Ab = Wt + (size_t)2 * DD * DD + (size_t)m * 256 * DD;
    Bb = xb + (size_t)b * SS * DD + (size_t)n * 256 * DD;
    Cb = VtB + (size_t)b * DD * SS + (size_t)m * 256 * SS + n * 256;
  }
  floatx4 acc[8][4];
  zero_acc8(acc);
  mm256_core(Ab, Bb, DD, DD, DD / 32,
             sA0, sA1, sA2, sA3, sB0, sB1, sB2, sB3, acc);
  store_c256_bf16(Cb, 2048, acc);
}

// ---------------- QK^T -> P' = exp(s) bf16 (causal tiles only) + row-sum partials ----------------
// 1D grid 1088: b = bid&7 (XCD==batch), tt = 135-(bid>>3) (qi descending).

__global__ __launch_bounds__(256) void qk_p(
    const bf16_t* __restrict__ Q, const bf16_t* __restrict__ K,
    bf16_t* __restrict__ P, float* __restrict__ lpart) {
  const int b  = blockIdx.x & 7;
  const int tt = 135 - (blockIdx.x >> 3);
  int qi = (int)((sqrtf(8.0f * tt + 1.0f) - 1.0f) * 0.5f);
  while ((qi + 1) * (qi + 2) / 2 <= tt) ++qi;
  while (qi * (qi + 1) / 2 > tt) --qi;
  const int ki = tt - qi * (qi + 1) / 2;

  MM128_LDS_DECL
  __shared__ float reds[2][128];
  const bf16_t* Ab = Q + ((size_t)b * SS + qi * 128) * (size_t)(2 * DD);
  const bf16_t* Bb = K + ((size_t)b * SS + ki * 128) * (size_t)(2 * DD);
  floatx4 acc[4][4];
  zero_acc(acc);
  mm_core2(Ab, Bb, 2 * DD, 2 * DD, DD / 64, sA0, sB0, sA1, sB1, acc);

  const int lane = threadIdx.x & 63;
  const int wm = (threadIdx.x >> 6) >> 1, wn = (threadIdx.x >> 6) & 1;
  const bool diag = (ki == qi);
  bf16_t* Pb = P + (size_t)b * SS * SS;
  const int qloc0 = wm * 64 + (lane & 15);        // + i*16
  const int kvb0  = wn * 64 + (lane >> 4) * 4;    // + j*16, + reg

#pragma unroll
  for (int i = 0; i < 4; ++i) {
    const int qrow = qloc0 + i * 16;
    float partial = 0.f;
#pragma unroll
    for (int j = 0; j < 4; ++j) {
      const int kvb = kvb0 + j * 16;
      floatx4 p;
#pragma unroll
      for (int r = 0; r < 4; ++r) {
        const float s = acc[i][j][r] * INV_SCALE;
        p[r] = (diag && (kvb + r) > qrow) ? 0.f : __expf(s);
        partial += p[r];
      }
      bf16x4 o = {(bf16_t)p[0], (bf16_t)p[1], (bf16_t)p[2], (bf16_t)p[3]};
      *(bf16x4*)(Pb + (size_t)(qi * 128 + qrow) * SS + ki * 128 + kvb) = o;
    }
    partial += __shfl_xor(partial, 16);
    partial += __shfl_xor(partial, 32);
    if ((lane >> 4) == 0) reds[wn][qrow] = partial;
  }
  __syncthreads();
  const int t = threadIdx.x;
  if (t < 128) {
    size_t row = (size_t)b * SS + qi * 128 + t;
    lpart[row * 16 + ki] = reds[0][t] + reds[1][t];
  }
}

// ---------------- PV GEMM (causal-truncated K-loop), rowsum+scale folded, fp32 out ----------------
// 1D grid 1024: b = bid&7 (XCD==batch), nj = (bid>>3)&7, qi = 15-(bid>>6) desc.

__global__ __launch_bounds__(256) void pv_gemm(
    const bf16_t* __restrict__ P, const bf16_t* __restrict__ Vt,
    const float* __restrict__ lpart, float* __restrict__ Out) {
  const int bid = blockIdx.x;
  const int b  = bid & 7;
  const int nj = (bid >> 3) & 7;
  const int qi = 15 - (bid >> 6);

  MM128_LDS_DECL
  __shared__ float sRl[128];
  const int t = threadIdx.x;
  if (t < 128) {
    const float* lp = lpart + ((size_t)b * SS + qi * 128 + t) * 16;
    float L = 0.f;
    for (int ci = 0; ci <= qi; ++ci) L += lp[ci];
    sRl[t] = 1.0f / L;
  }
  const bf16_t* Ab = P + (size_t)b * SS * SS + (size_t)qi * 128 * SS;
  const bf16_t* Bb = Vt + (size_t)b * DD * SS + (size_t)nj * 128 * SS;
  float* Cb = Out + (size_t)b * SS * DD + (size_t)qi * 128 * DD + nj * 128;
  floatx4 acc[4][4];
  zero_acc(acc);
  mm_core2(Ab, Bb, SS, SS, (qi + 1) * 2, sA0, sB0, sA1, sB1, acc); // K=(qi+1)*128
  const int lane = threadIdx.x & 63;
  const int wm = (threadIdx.x >> 6) >> 1, wn = (threadIdx.x >> 6) & 1;
  const int m0 = wm * 64 + (lane & 15);          // q row
  const int n0 = wn * 64 + (lane >> 4) * 4;      // dv col
#pragma unroll
  for (int i2 = 0; i2 < 4; ++i2) {
    const float scale = sRl[m0 + i2 * 16];
    float* crow = Cb + (size_t)(m0 + i2 * 16) * DD + n0;
#pragma unroll
    for (int j = 0; j < 4; ++j) {
      floatx4 o = acc[i2][j];
      o[0] *= scale; o[1] *= scale; o[2] *= scale; o[3] *= scale;
      *(floatx4*)(crow + j * 16) = o;
    }
  }
}

// ---------------- launch ----------------

extern "C" void kernel_launch(void* const* d_in, const int* in_sizes, int n_in,
                              void* d_out, int out_size, void* d_ws, size_t ws_size,
                              hipStream_t stream) {
  const float* x  = (const float*)d_in[0];
  const float* Wq = (const float*)d_in[1];
  const float* Wk = (const float*)d_in[2];
  const float* Wv = (const float*)d_in[3];
  float* out = (float*)d_out;

  char* ws = (char*)d_ws;
  bf16_t* xb   = (bf16_t*)(ws);                      // 33,554,432  x bf16 [B*S, D]
  bf16_t* Wt   = (bf16_t*)(ws + 33554432ull);        //  6,291,456  Wq^T,Wk^T,Wv^T bf16 [N,K] each
  bf16_t* QKb  = (bf16_t*)(ws + 39845888ull);        // 67,108,864  [Q|K] bf16 [B*S, 2048]
  bf16_t* VtB  = (bf16_t*)(ws + 106954752ull);       // 33,554,432  V^T bf16 [B, D, S]
  bf16_t* Pb   = (bf16_t*)(ws + 140509184ull);       // 67,108,864  P' bf16 [B, S, S] (causal area only)
  float*  lpart= (float*)(ws + 207618048ull);        //  1,048,576  row-sum partials [B*S, 16]
  (void)in_sizes; (void)n_in; (void)out_size; (void)ws_size;

  // 1. convert x + convert/transpose weights (one dispatch)
  prep<<<16384 + 3072, 256, 0, stream>>>(x, Wq, Wk, Wv, xb, Wt);
  // 2. FUSED: [Q|K] = x @ [Wq|Wk] (512 blocks) + V^T = Wv^T@x^T (256 blocks)
  proj_gemm<<<768, 512, 0, stream>>>(xb, Wt, QKb, VtB);
  // 3. P' = exp(QK^T/32) on causal tiles + row-sum partials, XCD==batch
  qk_p<<<1088, 256, 0, stream>>>(QKb, QKb + DD, Pb, lpart);
  // 4. out = (P' @ V) * (1/rowsum), causal K-truncation, XCD==batch, nj inner
  pv_gemm<<<1024, 256, 0, stream>>>(Pb, VtB, lpart, out);
}